// Round 4
// baseline (92.936 us; speedup 1.0000x reference)
//
#include <hip/hip_runtime.h>

#define HW 512
#define PADR 5
#define SEGS 64          // segments per image (ROWS = 8)
#define ROWS 8
#define WPB 4            // adjacent segments per block -> halo reuse in L1/L2

typedef float vfloat4 __attribute__((ext_vector_type(4)));

__device__ __forceinline__ void load8(const float* __restrict__ p, float v[8]) {
    float4 a = *(const float4*)p;
    float4 b = *(const float4*)(p + 4);
    v[0]=a.x; v[1]=a.y; v[2]=a.z; v[3]=a.w;
    v[4]=b.x; v[5]=b.y; v[6]=b.z; v[7]=b.w;
}

__device__ __forceinline__ void load8nt(const float* __restrict__ p, float v[8]) {
    vfloat4 a = __builtin_nontemporal_load((const vfloat4*)p);
    vfloat4 b = __builtin_nontemporal_load((const vfloat4*)p + 1);
    v[0]=a.x; v[1]=a.y; v[2]=a.z; v[3]=a.w;
    v[4]=b.x; v[5]=b.y; v[6]=b.z; v[7]=b.w;
}

__global__ __launch_bounds__(256, 6)
void std_loss_kernel(const float* __restrict__ pred,
                     const float* __restrict__ targ,
                     float* __restrict__ out, float invN)
{
    const int lane = threadIdx.x & 63;
    const int wib  = threadIdx.x >> 6;
    const int wid  = blockIdx.x * WPB + wib;
    const int img  = wid / SEGS;
    const int seg  = wid - img * SEGS;

    const float* T = targ + (size_t)img * (HW*HW);
    const float* P = pred + (size_t)img * (HW*HW);

    const int c0 = lane * 8;                 // wave covers the full 512-col row
    const int y0 = seg * ROWS;
    const int y1 = y0 + ROWS;

    // vertical 11-row window sums centered at y0 (replicate-y via clamp)
    float vs[8], vq[8];
    #pragma unroll
    for (int i = 0; i < 8; ++i) { vs[i] = 0.f; vq[i] = 0.f; }
    #pragma unroll
    for (int dy = -PADR; dy <= PADR; ++dy) {
        int ry = min(max(y0 + dy, 0), HW - 1);
        float t[8];
        load8(T + ry*HW + c0, t);
        #pragma unroll
        for (int i = 0; i < 8; ++i) { vs[i] += t[i]; vq[i] += t[i]*t[i]; }
    }

    // prefetch the critical stream: vn(y) = T[y+6]
    float vn[8];
    load8(T + min(y0 + PADR + 1, HW-1)*HW + c0, vn);

    const float inv = 1.0f / 121.0f;
    float acc = 0.f;

    for (int y = y0; y < y1; ++y) {
        // prefetch vn for NEXT iteration (2-iter slack on the critical chain)
        float vnn[8];
        load8(T + min(y + PADR + 2, HW-1)*HW + c0, vnn);

        float tv[8], pv[8], vo[8];
        load8  (T + y*HW + c0, tv);                  // L1/L2 hit (in window)
        load8nt(P + y*HW + c0, pv);                  // pure stream, bypass reuse
        load8  (T + max(y - PADR, 0)*HW + c0, vo);   // L1/L2 hit

        // cross-lane halo: prev lane's vs[3..7], next lane's vs[0..4]
        float ups[5], upq[5], dns[5], dnq[5];
        #pragma unroll
        for (int k = 0; k < 5; ++k) {
            float a = __shfl_up  (vs[3+k], 1, 64);
            float b = __shfl_up  (vq[3+k], 1, 64);
            float c = __shfl_down(vs[k],   1, 64);
            float d = __shfl_down(vq[k],   1, 64);
            ups[k] = (lane == 0)  ? vs[0] : a;       // replicate-x left
            upq[k] = (lane == 0)  ? vq[0] : b;
            dns[k] = (lane == 63) ? vs[7] : c;       // replicate-x right
            dnq[k] = (lane == 63) ? vq[7] : d;
        }

        float bs = ups[0]+ups[1]+ups[2]+ups[3]+ups[4]
                 + vs[0]+vs[1]+vs[2]+vs[3]+vs[4]+vs[5];
        float bq = upq[0]+upq[1]+upq[2]+upq[3]+upq[4]
                 + vq[0]+vq[1]+vq[2]+vq[3]+vq[4]+vq[5];

        auto emit = [&](int i, float s, float q) {
            float m   = s * inv;
            float var = fmaf(q, inv, -m*m);
            float sd  = sqrtf(fmaxf(var, 0.f));
            float w   = fmaf(fminf(sd, 0.4f), 5.0f, 1.0f);
            acc += fabsf(pv[i] - tv[i]) * w;
        };

        emit(0, bs, bq);
        bs += vs[6]  - ups[0];  bq += vq[6]  - upq[0];  emit(1, bs, bq);
        bs += vs[7]  - ups[1];  bq += vq[7]  - upq[1];  emit(2, bs, bq);
        bs += dns[0] - ups[2];  bq += dnq[0] - upq[2];  emit(3, bs, bq);
        bs += dns[1] - ups[3];  bq += dnq[1] - upq[3];  emit(4, bs, bq);
        bs += dns[2] - ups[4];  bq += dnq[2] - upq[4];  emit(5, bs, bq);
        bs += dns[3] - vs[0];   bq += dnq[3] - vq[0];   emit(6, bs, bq);
        bs += dns[4] - vs[1];   bq += dnq[4] - vq[1];   emit(7, bs, bq);

        // slide vertical window: +T[y+6] (prefetched), -T[y-5]
        #pragma unroll
        for (int i = 0; i < 8; ++i) {
            vs[i] += vn[i] - vo[i];
            vq[i] += vn[i]*vn[i] - vo[i]*vo[i];
        }
        #pragma unroll
        for (int i = 0; i < 8; ++i) vn[i] = vnn[i];
    }

    // wave reduce
    #pragma unroll
    for (int off = 32; off > 0; off >>= 1)
        acc += __shfl_down(acc, off, 64);

    __shared__ float wsum[WPB];
    if (lane == 0) wsum[wib] = acc;
    __syncthreads();
    if (threadIdx.x == 0) {
        float s = 0.f;
        #pragma unroll
        for (int i = 0; i < WPB; ++i) s += wsum[i];
        atomicAdd(out, s * invN);
    }
}

extern "C" void kernel_launch(void* const* d_in, const int* in_sizes, int n_in,
                              void* d_out, int out_size, void* d_ws, size_t ws_size,
                              hipStream_t stream) {
    const float* pred = (const float*)d_in[0];
    const float* targ = (const float*)d_in[1];
    float* out = (float*)d_out;

    const int nimg = in_sizes[1] / (HW * HW);       // 96 for (32,3,512,512)
    const float invN = 1.0f / (float)in_sizes[1];

    (void)hipMemsetAsync(out, 0, sizeof(float), stream);  // capture-legal memset node

    const int nblocks = nimg * SEGS / WPB;          // 1536 -> 6 blocks/CU
    std_loss_kernel<<<nblocks, 256, 0, stream>>>(pred, targ, out, invN);
}

// Round 5
// 77.636 us; speedup vs baseline: 1.1971x; 1.1971x over previous
//
#include <hip/hip_runtime.h>

#define HW 512
#define PADR 5
#define SEGS 32          // segments per image (ROWS = 16)
#define ROWS 16
#define WPB 4            // adjacent segments per block -> halo reuse in L1/L2

__device__ __forceinline__ void load8(const float* __restrict__ p, float v[8]) {
    float4 a = *(const float4*)p;
    float4 b = *(const float4*)(p + 4);
    v[0]=a.x; v[1]=a.y; v[2]=a.z; v[3]=a.w;
    v[4]=b.x; v[5]=b.y; v[6]=b.z; v[7]=b.w;
}

// DPP wave shifts: pure VALU, no DS pipe. bound_ctrl=true -> invalid lanes read 0
// (lane 0 for shr, lane 63 for shl) — callers override those lanes with selects.
__device__ __forceinline__ float dpp_up1(float x) {   // lane i <- lane i-1 (shfl_up 1)
    return __int_as_float(__builtin_amdgcn_update_dpp(
        0, __float_as_int(x), 0x138 /*wave_shr:1*/, 0xf, 0xf, true));
}
__device__ __forceinline__ float dpp_dn1(float x) {   // lane i <- lane i+1 (shfl_down 1)
    return __int_as_float(__builtin_amdgcn_update_dpp(
        0, __float_as_int(x), 0x130 /*wave_shl:1*/, 0xf, 0xf, true));
}

__global__ __launch_bounds__(256)
void std_loss_kernel(const float* __restrict__ pred,
                     const float* __restrict__ targ,
                     float* __restrict__ out, float invN)
{
    const int lane = threadIdx.x & 63;
    const int wib  = threadIdx.x >> 6;
    const int wid  = blockIdx.x * WPB + wib;
    const int img  = wid / SEGS;
    const int seg  = wid - img * SEGS;

    const float* T = targ + (size_t)img * (HW*HW);
    const float* P = pred + (size_t)img * (HW*HW);

    const int c0 = lane * 8;                 // wave covers the full 512-col row
    const int y0 = seg * ROWS;
    const int y1 = y0 + ROWS;
    const bool l0  = (lane == 0);
    const bool l63 = (lane == 63);

    // vertical 11-row window sums centered at y0 (replicate-y via clamp)
    float vs[8], vq[8];
    #pragma unroll
    for (int i = 0; i < 8; ++i) { vs[i] = 0.f; vq[i] = 0.f; }
    #pragma unroll
    for (int dy = -PADR; dy <= PADR; ++dy) {
        int ry = min(max(y0 + dy, 0), HW - 1);
        float t[8];
        load8(T + ry*HW + c0, t);
        #pragma unroll
        for (int i = 0; i < 8; ++i) { vs[i] += t[i]; vq[i] += t[i]*t[i]; }
    }

    // 1-deep prefetch of the critical stream: vn(y) = T[y+6]
    float vn[8];
    load8(T + min(y0 + PADR + 1, HW-1)*HW + c0, vn);

    const float inv = 1.0f / 121.0f;
    float acc = 0.f;

    for (int y = y0; y < y1; ++y) {
        // prefetch vn for NEXT iteration (chain slack)
        float vnn[8];
        load8(T + min(y + PADR + 2, HW-1)*HW + c0, vnn);

        float tv[8], pv[8], vo[8];
        load8(T + y*HW + c0, tv);                    // L1/L2 hit (in window)
        load8(P + y*HW + c0, pv);                    // HBM stream
        load8(T + max(y - PADR, 0)*HW + c0, vo);     // L1/L2 hit

        // cross-lane halo via DPP (VALU pipe): prev lane's vs[3..7], next lane's vs[0..4]
        float ups[5], upq[5], dns[5], dnq[5];
        #pragma unroll
        for (int k = 0; k < 5; ++k) {
            float a = dpp_up1(vs[3+k]);
            float b = dpp_up1(vq[3+k]);
            float c = dpp_dn1(vs[k]);
            float d = dpp_dn1(vq[k]);
            ups[k] = l0  ? vs[0] : a;                // replicate-x left
            upq[k] = l0  ? vq[0] : b;
            dns[k] = l63 ? vs[7] : c;                // replicate-x right
            dnq[k] = l63 ? vq[7] : d;
        }

        float bs = ups[0]+ups[1]+ups[2]+ups[3]+ups[4]
                 + vs[0]+vs[1]+vs[2]+vs[3]+vs[4]+vs[5];
        float bq = upq[0]+upq[1]+upq[2]+upq[3]+upq[4]
                 + vq[0]+vq[1]+vq[2]+vq[3]+vq[4]+vq[5];

        auto emit = [&](int i, float s, float q) {
            float m   = s * inv;
            float var = fmaf(q, inv, -m*m);
            float sd  = __builtin_amdgcn_sqrtf(fmaxf(var, 0.f));
            float w   = fminf(fmaf(sd, 5.0f, 1.0f), 3.0f);  // 1 + min(sd,0.4)*5
            acc += fabsf(pv[i] - tv[i]) * w;
        };

        emit(0, bs, bq);
        bs += vs[6]  - ups[0];  bq += vq[6]  - upq[0];  emit(1, bs, bq);
        bs += vs[7]  - ups[1];  bq += vq[7]  - upq[1];  emit(2, bs, bq);
        bs += dns[0] - ups[2];  bq += dnq[0] - upq[2];  emit(3, bs, bq);
        bs += dns[1] - ups[3];  bq += dnq[1] - upq[3];  emit(4, bs, bq);
        bs += dns[2] - ups[4];  bq += dnq[2] - upq[4];  emit(5, bs, bq);
        bs += dns[3] - vs[0];   bq += dnq[3] - vq[0];   emit(6, bs, bq);
        bs += dns[4] - vs[1];   bq += dnq[4] - vq[1];   emit(7, bs, bq);

        // slide vertical window: +T[y+6] (prefetched), -T[y-5]
        #pragma unroll
        for (int i = 0; i < 8; ++i) {
            float d = vn[i] - vo[i];
            float sdm = vn[i] + vo[i];
            vs[i] += d;
            vq[i] = fmaf(d, sdm, vq[i]);
        }
        #pragma unroll
        for (int i = 0; i < 8; ++i) vn[i] = vnn[i];
    }

    // wave reduce
    #pragma unroll
    for (int off = 32; off > 0; off >>= 1)
        acc += __shfl_down(acc, off, 64);

    __shared__ float wsum[WPB];
    if (lane == 0) wsum[wib] = acc;
    __syncthreads();
    if (threadIdx.x == 0) {
        float s = 0.f;
        #pragma unroll
        for (int i = 0; i < WPB; ++i) s += wsum[i];
        atomicAdd(out, s * invN);
    }
}

extern "C" void kernel_launch(void* const* d_in, const int* in_sizes, int n_in,
                              void* d_out, int out_size, void* d_ws, size_t ws_size,
                              hipStream_t stream) {
    const float* pred = (const float*)d_in[0];
    const float* targ = (const float*)d_in[1];
    float* out = (float*)d_out;

    const int nimg = in_sizes[1] / (HW * HW);       // 96 for (32,3,512,512)
    const float invN = 1.0f / (float)in_sizes[1];

    (void)hipMemsetAsync(out, 0, sizeof(float), stream);  // capture-legal memset node

    const int nblocks = nimg * SEGS / WPB;          // 768
    std_loss_kernel<<<nblocks, 256, 0, stream>>>(pred, targ, out, invN);
}

// Round 6
// 52.946 us; speedup vs baseline: 1.7553x; 1.4663x over previous
//
#include <hip/hip_runtime.h>

#define HW 512
#define PADR 5
#define SEGS 32          // segments per image (ROWS = 16)
#define ROWS 16
#define WPB 4            // adjacent segments per block -> halo reuse in L2

__device__ __forceinline__ void load8(const float* __restrict__ p, float v[8]) {
    float4 a = *(const float4*)p;
    float4 b = *(const float4*)(p + 4);
    v[0]=a.x; v[1]=a.y; v[2]=a.z; v[3]=a.w;
    v[4]=b.x; v[5]=b.y; v[6]=b.z; v[7]=b.w;
}

// DPP wave shifts: pure VALU, no DS pipe. bound_ctrl=true zeros invalid lanes;
// callers override lane 0 / lane 63 with selects (replicate padding).
__device__ __forceinline__ float dpp_up1(float x) {   // lane i <- lane i-1
    return __int_as_float(__builtin_amdgcn_update_dpp(
        0, __float_as_int(x), 0x138 /*wave_shr:1*/, 0xf, 0xf, true));
}
__device__ __forceinline__ float dpp_dn1(float x) {   // lane i <- lane i+1
    return __int_as_float(__builtin_amdgcn_update_dpp(
        0, __float_as_int(x), 0x130 /*wave_shl:1*/, 0xf, 0xf, true));
}

__global__ __launch_bounds__(256, 3)
void std_loss_kernel(const float* __restrict__ pred,
                     const float* __restrict__ targ,
                     float* __restrict__ out, float invN)
{
    const int lane = threadIdx.x & 63;
    const int wib  = threadIdx.x >> 6;
    const int wid  = blockIdx.x * WPB + wib;
    const int img  = wid / SEGS;
    const int seg  = wid - img * SEGS;

    const float* T = targ + (size_t)img * (HW*HW);
    const float* P = pred + (size_t)img * (HW*HW);

    const int c0 = lane * 8;                 // wave covers the full 512-col row
    const int y0 = seg * ROWS;
    const bool l0  = (lane == 0);
    const bool l63 = (lane == 63);

    // ---- 11-row register FIFO of T values: fifo[j] = T[clamp(y0-5+j)] ----
    float fifo[11][8];
    #pragma unroll
    for (int j = 0; j < 11; ++j) {
        int ry = min(max(y0 - PADR + j, 0), HW - 1);
        load8(T + ry*HW + c0, fifo[j]);
    }

    float vs[8], vq[8];
    #pragma unroll
    for (int c = 0; c < 8; ++c) {
        float s = 0.f, q = 0.f;
        #pragma unroll
        for (int j = 0; j < 11; ++j) { float t = fifo[j][c]; s += t; q = fmaf(t, t, q); }
        vs[c] = s; vq[c] = q;
    }

    float acc = 0.f;

    #pragma unroll
    for (int i = 0; i < ROWS; ++i) {
        // the only two VMEM streams (both pure HBM, scheduler-hoistable)
        float vn[8], pv[8];
        load8(T + min(y0 + i + PADR + 1, HW-1)*HW + c0, vn);
        load8(P + (y0 + i)*HW + c0, pv);

        // cross-lane halo via DPP: prev lane's vs[3..7], next lane's vs[0..4]
        float ups[5], upq[5], dns[5], dnq[5];
        #pragma unroll
        for (int k = 0; k < 5; ++k) {
            float a = dpp_up1(vs[3+k]);
            float b = dpp_up1(vq[3+k]);
            float c = dpp_dn1(vs[k]);
            float d = dpp_dn1(vq[k]);
            ups[k] = l0  ? vs[0] : a;
            upq[k] = l0  ? vq[0] : b;
            dns[k] = l63 ? vs[7] : c;
            dnq[k] = l63 ? vq[7] : d;
        }

        float bs = ups[0]+ups[1]+ups[2]+ups[3]+ups[4]
                 + vs[0]+vs[1]+vs[2]+vs[3]+vs[4]+vs[5];
        float bq = upq[0]+upq[1]+upq[2]+upq[3]+upq[4]
                 + vq[0]+vq[1]+vq[2]+vq[3]+vq[4]+vq[5];

        // w = 1 + sqrt(clamp(25*var, 0, 4));  25*var = bq*25/121 - (bs*5/121)^2
#define EMIT(C) do { \
            float u = bs * (5.0f/121.0f); \
            float t = fmaf(bq, 25.0f/121.0f, -u*u); \
            t = fminf(fmaxf(t, 0.0f), 4.0f); \
            float w = 1.0f + __builtin_amdgcn_sqrtf(t); \
            acc = fmaf(fabsf(pv[C] - fifo[(i+5)%11][C]), w, acc); \
        } while (0)

        EMIT(0);
        bs += vs[6]  - ups[0];  bq += vq[6]  - upq[0];  EMIT(1);
        bs += vs[7]  - ups[1];  bq += vq[7]  - upq[1];  EMIT(2);
        bs += dns[0] - ups[2];  bq += dnq[0] - upq[2];  EMIT(3);
        bs += dns[1] - ups[3];  bq += dnq[1] - upq[3];  EMIT(4);
        bs += dns[2] - ups[4];  bq += dnq[2] - upq[4];  EMIT(5);
        bs += dns[3] - vs[0];   bq += dnq[3] - vq[0];   EMIT(6);
        bs += dns[4] - vs[1];   bq += dnq[4] - vq[1];   EMIT(7);
#undef EMIT

        // slide window: +row y+6 (vn), -row y-5 (FIFO slot i%11), rotate FIFO
        #pragma unroll
        for (int c = 0; c < 8; ++c) {
            float vnv = vn[c];
            float vov = fifo[i % 11][c];
            float d   = vnv - vov;
            vs[c] += d;
            vq[c]  = fmaf(d, vnv + vov, vq[c]);
            fifo[i % 11][c] = vnv;
        }
    }

    // wave reduce
    #pragma unroll
    for (int off = 32; off > 0; off >>= 1)
        acc += __shfl_down(acc, off, 64);

    __shared__ float wsum[WPB];
    if (lane == 0) wsum[wib] = acc;
    __syncthreads();
    if (threadIdx.x == 0) {
        float s = 0.f;
        #pragma unroll
        for (int i = 0; i < WPB; ++i) s += wsum[i];
        atomicAdd(out, s * invN);
    }
}

extern "C" void kernel_launch(void* const* d_in, const int* in_sizes, int n_in,
                              void* d_out, int out_size, void* d_ws, size_t ws_size,
                              hipStream_t stream) {
    const float* pred = (const float*)d_in[0];
    const float* targ = (const float*)d_in[1];
    float* out = (float*)d_out;

    const int nimg = in_sizes[1] / (HW * HW);       // 96 for (32,3,512,512)
    const float invN = 1.0f / (float)in_sizes[1];

    (void)hipMemsetAsync(out, 0, sizeof(float), stream);  // capture-legal memset node

    const int nblocks = nimg * SEGS / WPB;          // 768
    std_loss_kernel<<<nblocks, 256, 0, stream>>>(pred, targ, out, invN);
}

// Round 7
// 52.528 us; speedup vs baseline: 1.7693x; 1.0080x over previous
//
#include <hip/hip_runtime.h>

#define HW 512
#define PADR 5
#define SEGS 32          // segments per image (ROWS = 16)
#define ROWS 16
#define WPB 4            // adjacent segments per block -> halo reuse in L2/L3

__device__ __forceinline__ void load8(const float* __restrict__ p, float v[8]) {
    float4 a = *(const float4*)p;
    float4 b = *(const float4*)(p + 4);
    v[0]=a.x; v[1]=a.y; v[2]=a.z; v[3]=a.w;
    v[4]=b.x; v[5]=b.y; v[6]=b.z; v[7]=b.w;
}

// DPP wave shifts: pure VALU, no DS pipe. bound_ctrl=true zeros invalid lanes;
// callers override lane 0 / lane 63 with selects (replicate padding).
__device__ __forceinline__ float dpp_up1(float x) {   // lane i <- lane i-1
    return __int_as_float(__builtin_amdgcn_update_dpp(
        0, __float_as_int(x), 0x138 /*wave_shr:1*/, 0xf, 0xf, true));
}
__device__ __forceinline__ float dpp_dn1(float x) {   // lane i <- lane i+1
    return __int_as_float(__builtin_amdgcn_update_dpp(
        0, __float_as_int(x), 0x130 /*wave_shl:1*/, 0xf, 0xf, true));
}

__global__ __launch_bounds__(256, 3)
void std_loss_kernel(const float* __restrict__ pred,
                     const float* __restrict__ targ,
                     float* __restrict__ out, float invN)
{
    const int lane = threadIdx.x & 63;
    const int wib  = threadIdx.x >> 6;
    const int wid  = blockIdx.x * WPB + wib;
    const int img  = wid / SEGS;
    const int seg  = wid - img * SEGS;

    const float* T = targ + (size_t)img * (HW*HW);
    const float* P = pred + (size_t)img * (HW*HW);

    const int c0 = lane * 8;                 // wave covers the full 512-col row
    const int y0 = seg * ROWS;
    const bool l0  = (lane == 0);
    const bool l63 = (lane == 63);

    // ---- 11-row register FIFO of T values: fifo[j] = T[clamp(y0-5+j)] ----
    float fifo[11][8];
    #pragma unroll
    for (int j = 0; j < 11; ++j) {
        int ry = min(max(y0 - PADR + j, 0), HW - 1);
        load8(T + ry*HW + c0, fifo[j]);
    }

    float vs[8], vq[8];
    #pragma unroll
    for (int c = 0; c < 8; ++c) {
        float s = 0.f, q = 0.f;
        #pragma unroll
        for (int j = 0; j < 11; ++j) { float t = fifo[j][c]; s += t; q = fmaf(t, t, q); }
        vs[c] = s; vq[c] = q;
    }

    // ---- explicit 2-deep A/B prefetch pipeline for the two HBM streams ----
    float vnbuf[2][8], pvbuf[2][8];
    load8(T + min(y0 + 0 + PADR + 1, HW-1)*HW + c0, vnbuf[0]);
    load8(P + (y0 + 0)*HW + c0, pvbuf[0]);
    load8(T + min(y0 + 1 + PADR + 1, HW-1)*HW + c0, vnbuf[1]);
    load8(P + (y0 + 1)*HW + c0, pvbuf[1]);

    float acc = 0.f;

    #pragma unroll
    for (int i = 0; i < ROWS; ++i) {
        const int cur = i & 1;               // compile-time after full unroll

        // cross-lane halo via DPP: prev lane's vs[3..7], next lane's vs[0..4]
        float ups[5], upq[5], dns[5], dnq[5];
        #pragma unroll
        for (int k = 0; k < 5; ++k) {
            float a = dpp_up1(vs[3+k]);
            float b = dpp_up1(vq[3+k]);
            float c = dpp_dn1(vs[k]);
            float d = dpp_dn1(vq[k]);
            ups[k] = l0  ? vs[0] : a;
            upq[k] = l0  ? vq[0] : b;
            dns[k] = l63 ? vs[7] : c;
            dnq[k] = l63 ? vq[7] : d;
        }

        float bs = ups[0]+ups[1]+ups[2]+ups[3]+ups[4]
                 + vs[0]+vs[1]+vs[2]+vs[3]+vs[4]+vs[5];
        float bq = upq[0]+upq[1]+upq[2]+upq[3]+upq[4]
                 + vq[0]+vq[1]+vq[2]+vq[3]+vq[4]+vq[5];

        // w = 1 + sqrt(clamp(25*var, 0, 4));  25*var = bq*25/121 - (bs*5/121)^2
#define EMIT(C) do { \
            float u = bs * (5.0f/121.0f); \
            float t = fmaf(bq, 25.0f/121.0f, -u*u); \
            t = fminf(fmaxf(t, 0.0f), 4.0f); \
            float w = 1.0f + __builtin_amdgcn_sqrtf(t); \
            acc = fmaf(fabsf(pvbuf[cur][C] - fifo[(i+5)%11][C]), w, acc); \
        } while (0)

        EMIT(0);
        bs += vs[6]  - ups[0];  bq += vq[6]  - upq[0];  EMIT(1);
        bs += vs[7]  - ups[1];  bq += vq[7]  - upq[1];  EMIT(2);
        bs += dns[0] - ups[2];  bq += dnq[0] - upq[2];  EMIT(3);
        bs += dns[1] - ups[3];  bq += dnq[1] - upq[3];  EMIT(4);
        bs += dns[2] - ups[4];  bq += dnq[2] - upq[4];  EMIT(5);
        bs += dns[3] - vs[0];   bq += dnq[3] - vq[0];   EMIT(6);
        bs += dns[4] - vs[1];   bq += dnq[4] - vq[1];   EMIT(7);
#undef EMIT

        // slide window: +row y+6 (vnbuf[cur]), -row y-5 (FIFO slot i%11)
        #pragma unroll
        for (int c = 0; c < 8; ++c) {
            float vnv = vnbuf[cur][c];
            float vov = fifo[i % 11][c];
            float d   = vnv - vov;
            vs[c] += d;
            vq[c]  = fmaf(d, vnv + vov, vq[c]);
            fifo[i % 11][c] = vnv;
        }

        // buffer `cur` is now free: issue iter i+2's loads into it (stay in flight
        // across all of iter i+1's compute)
        if (i + 2 < ROWS) {
            load8(T + min(y0 + (i+2) + PADR + 1, HW-1)*HW + c0, vnbuf[cur]);
            load8(P + (y0 + (i+2))*HW + c0, pvbuf[cur]);
        }
    }

    // wave reduce
    #pragma unroll
    for (int off = 32; off > 0; off >>= 1)
        acc += __shfl_down(acc, off, 64);

    __shared__ float wsum[WPB];
    if (lane == 0) wsum[wib] = acc;
    __syncthreads();
    if (threadIdx.x == 0) {
        float s = 0.f;
        #pragma unroll
        for (int i = 0; i < WPB; ++i) s += wsum[i];
        atomicAdd(out, s * invN);
    }
}

extern "C" void kernel_launch(void* const* d_in, const int* in_sizes, int n_in,
                              void* d_out, int out_size, void* d_ws, size_t ws_size,
                              hipStream_t stream) {
    const float* pred = (const float*)d_in[0];
    const float* targ = (const float*)d_in[1];
    float* out = (float*)d_out;

    const int nimg = in_sizes[1] / (HW * HW);       // 96 for (32,3,512,512)
    const float invN = 1.0f / (float)in_sizes[1];

    (void)hipMemsetAsync(out, 0, sizeof(float), stream);  // capture-legal memset node

    const int nblocks = nimg * SEGS / WPB;          // 768
    std_loss_kernel<<<nblocks, 256, 0, stream>>>(pred, targ, out, invN);
}

// Round 8
// 51.148 us; speedup vs baseline: 1.8170x; 1.0270x over previous
//
#include <hip/hip_runtime.h>

#define HW 512
#define PADR 5
#define SEGS 32          // segments per image (ROWS = 16)
#define ROWS 16
#define WPB 4            // adjacent segments per block -> halo reuse in L2/L3

typedef _Float16 h2 __attribute__((ext_vector_type(2)));

__device__ __forceinline__ void load8(const float* __restrict__ p, float v[8]) {
    float4 a = *(const float4*)p;
    float4 b = *(const float4*)(p + 4);
    v[0]=a.x; v[1]=a.y; v[2]=a.z; v[3]=a.w;
    v[4]=b.x; v[5]=b.y; v[6]=b.z; v[7]=b.w;
}

// DPP wave shifts: pure VALU, no DS pipe. bound_ctrl=true zeros invalid lanes;
// callers override lane 0 / lane 63 with selects (replicate padding).
__device__ __forceinline__ float dpp_up1(float x) {   // lane i <- lane i-1
    return __int_as_float(__builtin_amdgcn_update_dpp(
        0, __float_as_int(x), 0x138 /*wave_shr:1*/, 0xf, 0xf, true));
}
__device__ __forceinline__ float dpp_dn1(float x) {   // lane i <- lane i+1
    return __int_as_float(__builtin_amdgcn_update_dpp(
        0, __float_as_int(x), 0x130 /*wave_shl:1*/, 0xf, 0xf, true));
}

__global__ __launch_bounds__(256, 3)
void std_loss_kernel(const float* __restrict__ pred,
                     const float* __restrict__ targ,
                     float* __restrict__ out, float invN)
{
    const int lane = threadIdx.x & 63;
    const int wib  = threadIdx.x >> 6;
    const int wid  = blockIdx.x * WPB + wib;
    const int img  = wid / SEGS;
    const int seg  = wid - img * SEGS;

    const float* T = targ + (size_t)img * (HW*HW);
    const float* P = pred + (size_t)img * (HW*HW);

    const int c0 = lane * 8;                 // wave covers the full 512-col row
    const int y0 = seg * ROWS;
    const bool l0  = (lane == 0);
    const bool l63 = (lane == 63);

    // ---- 11-row fp16-packed register FIFO: fifo[j] = quantized T[clamp(y0-5+j)] ----
    // 44 VGPRs instead of 88 — must be register-resident. All statistics use the
    // quantized values uniformly, so window add/subtract cancels exactly.
    h2 fifo[11][4];
    float vs[8], vq[8];
    #pragma unroll
    for (int c = 0; c < 8; ++c) { vs[c] = 0.f; vq[c] = 0.f; }
    #pragma unroll
    for (int j = 0; j < 11; ++j) {
        int ry = min(max(y0 - PADR + j, 0), HW - 1);
        float t[8];
        load8(T + ry*HW + c0, t);
        #pragma unroll
        for (int c = 0; c < 4; ++c) {
            h2 v; v.x = (_Float16)t[2*c]; v.y = (_Float16)t[2*c+1];
            fifo[j][c] = v;
            float q0 = (float)v.x, q1 = (float)v.y;
            vs[2*c]   += q0; vq[2*c]   = fmaf(q0, q0, vq[2*c]);
            vs[2*c+1] += q1; vq[2*c+1] = fmaf(q1, q1, vq[2*c+1]);
        }
    }

    // ---- explicit 2-deep A/B prefetch pipeline for the two HBM streams ----
    float vnbuf[2][8], pvbuf[2][8];
    load8(T + min(y0 + 0 + PADR + 1, HW-1)*HW + c0, vnbuf[0]);
    load8(P + (y0 + 0)*HW + c0, pvbuf[0]);
    load8(T + min(y0 + 1 + PADR + 1, HW-1)*HW + c0, vnbuf[1]);
    load8(P + (y0 + 1)*HW + c0, pvbuf[1]);

    float acc = 0.f;

    #pragma unroll
    for (int i = 0; i < ROWS; ++i) {
        const int cur = i & 1;               // compile-time after full unroll

        // cross-lane halo via DPP: prev lane's vs[3..7], next lane's vs[0..4]
        float ups[5], upq[5], dns[5], dnq[5];
        #pragma unroll
        for (int k = 0; k < 5; ++k) {
            float a = dpp_up1(vs[3+k]);
            float b = dpp_up1(vq[3+k]);
            float c = dpp_dn1(vs[k]);
            float d = dpp_dn1(vq[k]);
            ups[k] = l0  ? vs[0] : a;
            upq[k] = l0  ? vq[0] : b;
            dns[k] = l63 ? vs[7] : c;
            dnq[k] = l63 ? vq[7] : d;
        }

        float bs = ups[0]+ups[1]+ups[2]+ups[3]+ups[4]
                 + vs[0]+vs[1]+vs[2]+vs[3]+vs[4]+vs[5];
        float bq = upq[0]+upq[1]+upq[2]+upq[3]+upq[4]
                 + vq[0]+vq[1]+vq[2]+vq[3]+vq[4]+vq[5];

        // center row (quantized) for the |p - t| term
        float tvq[8];
        #pragma unroll
        for (int c = 0; c < 4; ++c) {
            h2 v = fifo[(i+5) % 11][c];
            tvq[2*c] = (float)v.x; tvq[2*c+1] = (float)v.y;
        }

        // w = 1 + sqrt(clamp(25*var, 0, 4));  25*var = bq*25/121 - (bs*5/121)^2
#define EMIT(C) do { \
            float u = bs * (5.0f/121.0f); \
            float t = fmaf(bq, 25.0f/121.0f, -u*u); \
            t = fminf(fmaxf(t, 0.0f), 4.0f); \
            float w = 1.0f + __builtin_amdgcn_sqrtf(t); \
            acc = fmaf(fabsf(pvbuf[cur][C] - tvq[C]), w, acc); \
        } while (0)

        EMIT(0);
        bs += vs[6]  - ups[0];  bq += vq[6]  - upq[0];  EMIT(1);
        bs += vs[7]  - ups[1];  bq += vq[7]  - upq[1];  EMIT(2);
        bs += dns[0] - ups[2];  bq += dnq[0] - upq[2];  EMIT(3);
        bs += dns[1] - ups[3];  bq += dnq[1] - upq[3];  EMIT(4);
        bs += dns[2] - ups[4];  bq += dnq[2] - upq[4];  EMIT(5);
        bs += dns[3] - vs[0];   bq += dnq[3] - vq[0];   EMIT(6);
        bs += dns[4] - vs[1];   bq += dnq[4] - vq[1];   EMIT(7);
#undef EMIT

        // slide window: quantize incoming row, +quantized(y+6), -fifo slot (y-5)
        #pragma unroll
        for (int c = 0; c < 4; ++c) {
            h2 nv; nv.x = (_Float16)vnbuf[cur][2*c]; nv.y = (_Float16)vnbuf[cur][2*c+1];
            h2 ov = fifo[i % 11][c];
            float n0 = (float)nv.x, n1 = (float)nv.y;
            float o0 = (float)ov.x, o1 = (float)ov.y;
            float d0 = n0 - o0, d1 = n1 - o1;
            vs[2*c]   += d0;  vq[2*c]   = fmaf(d0, n0 + o0, vq[2*c]);
            vs[2*c+1] += d1;  vq[2*c+1] = fmaf(d1, n1 + o1, vq[2*c+1]);
            fifo[i % 11][c] = nv;
        }

        // buffer `cur` is free: issue iter i+2's loads (in flight across iter i+1)
        if (i + 2 < ROWS) {
            load8(T + min(y0 + (i+2) + PADR + 1, HW-1)*HW + c0, vnbuf[cur]);
            load8(P + (y0 + (i+2))*HW + c0, pvbuf[cur]);
        }
    }

    // wave reduce
    #pragma unroll
    for (int off = 32; off > 0; off >>= 1)
        acc += __shfl_down(acc, off, 64);

    __shared__ float wsum[WPB];
    if (lane == 0) wsum[wib] = acc;
    __syncthreads();
    if (threadIdx.x == 0) {
        float s = 0.f;
        #pragma unroll
        for (int i = 0; i < WPB; ++i) s += wsum[i];
        atomicAdd(out, s * invN);
    }
}

extern "C" void kernel_launch(void* const* d_in, const int* in_sizes, int n_in,
                              void* d_out, int out_size, void* d_ws, size_t ws_size,
                              hipStream_t stream) {
    const float* pred = (const float*)d_in[0];
    const float* targ = (const float*)d_in[1];
    float* out = (float*)d_out;

    const int nimg = in_sizes[1] / (HW * HW);       // 96 for (32,3,512,512)
    const float invN = 1.0f / (float)in_sizes[1];

    (void)hipMemsetAsync(out, 0, sizeof(float), stream);  // capture-legal memset node

    const int nblocks = nimg * SEGS / WPB;          // 768
    std_loss_kernel<<<nblocks, 256, 0, stream>>>(pred, targ, out, invN);
}